// Round 7
// baseline (435.085 us; speedup 1.0000x reference)
//
#include <hip/hip_runtime.h>
#include <stdint.h>
#include <stddef.h>

// Problem constants
#define BB 4
#define CC 256
#define NH 8
#define DH 32
#define NN 2304      // 48*48
#define O3 768
#define HID 256
#define QK_SCALE 0.17677669529663687f  // 32^-0.5
#define LOG2E 1.44269504f

typedef __attribute__((ext_vector_type(8))) short short8;
typedef __attribute__((ext_vector_type(4))) float float4v;

__device__ __forceinline__ unsigned short f2bf(float f) {
    union { float f; uint32_t u; } v; v.f = f;
    uint32_t u = v.u;
    return (unsigned short)((u + 0x7FFFu + ((u >> 16) & 1u)) >> 16);   // RNE
}
__device__ __forceinline__ float bf2f(unsigned short s) {
    union { uint32_t u; float f; } v; v.u = ((uint32_t)s) << 16;
    return v.f;
}

// ---------------------------------------------------------------------------
// K0: prep = transpose-cast x -> xT bf16  (blocks 0..2303)
//          + cast w_qkv hi/lo, w_out      (blocks 2304..3071)
// ---------------------------------------------------------------------------
__global__ __launch_bounds__(256) void prep_kernel(const float* __restrict__ x,
                                                   const float* __restrict__ wqkv,
                                                   const float* __restrict__ wout,
                                                   unsigned short* __restrict__ xT,
                                                   unsigned short* __restrict__ whi,
                                                   unsigned short* __restrict__ wlo,
                                                   unsigned short* __restrict__ wob) {
    const int bid = blockIdx.x;
    const int t = threadIdx.x;
    if (bid < 2304) {      // transpose 32x32 tile of x
        const int n0 = (bid % 72) * 32, c0 = ((bid / 72) % 8) * 32, b = bid / 576;
        __shared__ float ls[32][33];
        {
            int c = t >> 3, nc = (t & 7) * 4;
            float4 v4 = *(const float4*)(x + ((size_t)b * CC + c0 + c) * NN + n0 + nc);
            ls[c][nc] = v4.x; ls[c][nc + 1] = v4.y; ls[c][nc + 2] = v4.z; ls[c][nc + 3] = v4.w;
        }
        __syncthreads();
        {
            int n = t >> 3, cl = (t & 7) * 4;
            uint32_t p0 = (uint32_t)f2bf(ls[cl + 0][n]) | ((uint32_t)f2bf(ls[cl + 1][n]) << 16);
            uint32_t p1 = (uint32_t)f2bf(ls[cl + 2][n]) | ((uint32_t)f2bf(ls[cl + 3][n]) << 16);
            uint32_t* dst = (uint32_t*)(xT + ((size_t)b * NN + n0 + n) * CC + c0 + cl);
            dst[0] = p0; dst[1] = p1;
        }
    } else {               // weight casts
        int i = (bid - 2304) * 256 + t;
        float wv = wqkv[i];
        unsigned short hi = f2bf(wv);
        whi[i] = hi;
        wlo[i] = f2bf(wv - bf2f(hi));
        if (i < HID * HID) wob[i] = f2bf(wout[i]);
    }
}

// ---------------------------------------------------------------------------
// K1: fused QKV projection, bf16 MFMA, writes q/k/v directly in final layouts.
//   q,k bf16 [b][h][n][32] (q scaled by QK_SCALE*LOG2E), v bf16 [b][h][32][n]
// ---------------------------------------------------------------------------
__global__ __launch_bounds__(256) void qkv_gemm_bf16(const unsigned short* __restrict__ xT,
                                                     const unsigned short* __restrict__ whi,
                                                     const unsigned short* __restrict__ wlo,
                                                     unsigned short* __restrict__ q,
                                                     unsigned short* __restrict__ k,
                                                     unsigned short* __restrict__ v) {
    const int og = blockIdx.x;
    const int n0 = blockIdx.y * 64;
    const int b  = blockIdx.z;
    const int t = threadIdx.x;
    const int w = t >> 6, lane = t & 63, l15 = lane & 15, quad = lane >> 4;
    const unsigned short* xb = xT + (size_t)b * NN * CC;

    float4v acc[4] = {{0.f,0.f,0.f,0.f},{0.f,0.f,0.f,0.f},
                      {0.f,0.f,0.f,0.f},{0.f,0.f,0.f,0.f}};

    if (og < 8) {   // ---- qk mode: A = xT rows n, B = w rows o ----
        const int o0 = og * 64;
        const unsigned short* ap = xb + (size_t)(n0 + w * 16 + l15) * CC + quad * 8;
        #pragma unroll
        for (int c0 = 0; c0 < CC; c0 += 32) {
            short8 af = *(const short8*)(ap + c0);
            #pragma unroll
            for (int jj = 0; jj < 4; ++jj) {
                const size_t wo = (size_t)(o0 + jj * 16 + l15) * CC + c0 + quad * 8;
                short8 bh = *(const short8*)(whi + wo);
                short8 bl = *(const short8*)(wlo + wo);
                acc[jj] = __builtin_amdgcn_mfma_f32_16x16x32_bf16(af, bh, acc[jj], 0, 0, 0);
                acc[jj] = __builtin_amdgcn_mfma_f32_16x16x32_bf16(af, bl, acc[jj], 0, 0, 0);
            }
        }
        #pragma unroll
        for (int jj = 0; jj < 4; ++jj) {
            const int o = o0 + jj * 16 + l15;
            const int which = o >> 8;            // 0=q 1=k
            const int h = (o >> 5) & 7, d = o & 31;
            unsigned short* dst = which ? k : q;
            const float sc = which ? 1.0f : QK_SCALE * LOG2E;
            #pragma unroll
            for (int r = 0; r < 4; ++r) {
                const int n = n0 + w * 16 + quad * 4 + r;
                dst[(((size_t)b * NH + h) * NN + n) * DH + d] = f2bf(acc[jj][r] * sc);
            }
        }
    } else {        // ---- v mode: A = w rows o, B = xT rows n ----
        const int o0 = 512 + (og - 8) * 64;
        const size_t wr = (size_t)(o0 + w * 16 + l15) * CC + quad * 8;
        #pragma unroll
        for (int c0 = 0; c0 < CC; c0 += 32) {
            short8 ah = *(const short8*)(whi + wr + c0);
            short8 al = *(const short8*)(wlo + wr + c0);
            #pragma unroll
            for (int jj = 0; jj < 4; ++jj) {
                short8 bf = *(const short8*)(xb + (size_t)(n0 + jj * 16 + l15) * CC + c0 + quad * 8);
                acc[jj] = __builtin_amdgcn_mfma_f32_16x16x32_bf16(ah, bf, acc[jj], 0, 0, 0);
                acc[jj] = __builtin_amdgcn_mfma_f32_16x16x32_bf16(al, bf, acc[jj], 0, 0, 0);
            }
        }
        #pragma unroll
        for (int r = 0; r < 4; ++r) {
            const int o = o0 + w * 16 + quad * 4 + r;
            const int h = (o >> 5) & 7, d = o & 31;
            #pragma unroll
            for (int jj = 0; jj < 4; ++jj) {
                const int n = n0 + jj * 16 + l15;
                v[(((size_t)b * NH + h) * DH + d) * NN + n] = f2bf(acc[jj][r]);
            }
        }
    }
}

// ---------------------------------------------------------------------------
// K2: fused attention v7 — BARRIER-FREE, register-resident bias pipeline.
// Post-mortem r2/r4/r6: dur pinned at ~178us across three structures because
// the per-iteration __syncthreads forces s_waitcnt vmcnt(0): bias prefetch
// drains every iteration -> avg outstanding HBM bytes/CU ~ few KB -> bias
// stream runs at 750 GB/s (latency-bound), 90% wave stall.
// v7: NO __syncthreads in the kernel. Each wave loads its own bias C-fragment
// (32 fp32/lane: row=quad*4+r, col=jj*16+l15 -- exactly its MFMA C elements,
// layout proven in r4/r6) directly global->registers, double-buffered via a
// 2-phase unrolled loop: tile i+1's 32 loads issue during tile i's compute,
// consumed one full iteration later. Loads stay in flight across iterations
// (counted vmcnt only). The 4 batch-waves of a block read identical bias
// addresses ~in step -> L1/L2 dedup, HBM demand stays ~170MB read-once.
// ps remains wave-private (same-wave DS ordering, v0-proven, no barrier).
// grid (NN/16=144, NH=8), block 256 (wave = batch).
// ---------------------------------------------------------------------------
__global__ __launch_bounds__(256) void attn_kernel(const unsigned short* __restrict__ qg,
                                                   const unsigned short* __restrict__ kg,
                                                   const unsigned short* __restrict__ vg,
                                                   const float* __restrict__ bias,
                                                   unsigned short* __restrict__ ao) {
    const int i0   = blockIdx.x * 16;
    const int h    = blockIdx.y;
    const int t    = threadIdx.x;
    const int b    = t >> 6;            // wave index = batch index (BB==4)
    const int lane = t & 63;
    const int l15  = lane & 15;
    const int quad = lane >> 4;

    __shared__ unsigned short ps[BB][16][136];   // 17.4 KB, wave-private rows

    const size_t bh = (size_t)b * NH + h;
    const unsigned short* qp = qg + bh * NN * DH;
    const unsigned short* kp = kg + bh * NN * DH;
    const unsigned short* vp = vg + bh * DH * NN;

    short8 qf = *(const short8*)(qp + (size_t)(i0 + l15) * DH + quad * 8);

    float4v oa0 = {0.f, 0.f, 0.f, 0.f};
    float4v oa1 = {0.f, 0.f, 0.f, 0.f};
    float l_r[4] = {0.f, 0.f, 0.f, 0.f};

    // per-lane bias base: element (r,jj) of tile jt lives at
    // bp[r*NN + jt + jj*16]  (row i0+quad*4+r, col jt+jj*16+l15)
    const float* bp = bias + ((size_t)h * NN + i0 + quad * 4) * NN + l15;

    // prologue: bias tile 0 into ba (32 scalar fp32, 4x64B segments per instr)
    float ba[32], bb[32];
    #pragma unroll
    for (int r = 0; r < 4; ++r)
        #pragma unroll
        for (int jj = 0; jj < 8; ++jj)
            ba[r * 8 + jj] = bp[(size_t)r * NN + jj * 16];

#define ATTN_PHASE(BC, BN, JT, PJT, HAVEP)                                         \
{                                                                                  \
    /* K for THIS tile (L2-warm; covered by the load-issue shadow below) */        \
    short8 kf[8];                                                                  \
    _Pragma("unroll")                                                              \
    for (int jj = 0; jj < 8; ++jj)                                                 \
        kf[jj] = *(const short8*)(kp + (size_t)((JT) + jj * 16 + l15) * DH + quad * 8); \
    /* V for THIS tile: issued early, consumed at PV */                            \
    short8 vv[8];                                                                  \
    _Pragma("unroll")                                                              \
    for (int cc = 0; cc < 4; ++cc) {                                               \
        vv[2*cc]   = *(const short8*)(vp + (size_t)l15 * NN      + (JT) + cc*32 + quad*8); \
        vv[2*cc+1] = *(const short8*)(vp + (size_t)(l15+16) * NN + (JT) + cc*32 + quad*8); \
    }                                                                              \
    /* bias loads for NEXT tile: in flight across the whole iteration */           \
    if (HAVEP) {                                                                   \
        _Pragma("unroll")                                                          \
        for (int r = 0; r < 4; ++r)                                                \
            _Pragma("unroll")                                                      \
            for (int jj = 0; jj < 8; ++jj)                                         \
                BN[r * 8 + jj] = bp[(size_t)r * NN + (PJT) + jj * 16];             \
    }                                                                              \
    /* S = Q K^T with bias*LOG2E as C-init (q pre-scaled by SCALE*LOG2E) */        \
    float4v s[8];                                                                  \
    _Pragma("unroll")                                                              \
    for (int jj = 0; jj < 8; ++jj) {                                               \
        float4v ci = { BC[0*8+jj] * LOG2E, BC[1*8+jj] * LOG2E,                     \
                       BC[2*8+jj] * LOG2E, BC[3*8+jj] * LOG2E };                   \
        s[jj] = __builtin_amdgcn_mfma_f32_16x16x32_bf16(qf, kf[jj], ci, 0, 0, 0);  \
    }                                                                              \
    /* p = exp2(s); pack pairs to bf16 (RNE); per-lane row partial sums */         \
    _Pragma("unroll")                                                              \
    for (int r = 0; r < 4; ++r) {                                                  \
        const int row = quad * 4 + r;                                              \
        float pv_[8];                                                              \
        _Pragma("unroll")                                                          \
        for (int jj = 0; jj < 8; ++jj) { pv_[jj] = exp2f(s[jj][r]); l_r[r] += pv_[jj]; } \
        _Pragma("unroll")                                                          \
        for (int jp = 0; jp < 4; ++jp) {                                           \
            uint32_t pk;                                                           \
            asm("v_cvt_pk_bf16_f32 %0, %1, %2" : "=v"(pk) : "v"(pv_[2*jp]), "v"(pv_[2*jp+1])); \
            ps[b][row][(2*jp)   * 16 + l15] = (unsigned short)pk;                  \
            ps[b][row][(2*jp+1) * 16 + l15] = (unsigned short)(pk >> 16);          \
        }                                                                          \
    }                                                                              \
    /* O += P x V (ps wave-private: same-wave DS ordering, no barrier) */          \
    _Pragma("unroll")                                                              \
    for (int cc = 0; cc < 4; ++cc) {                                               \
        short8 pa = *(const short8*)&ps[b][l15][cc * 32 + quad * 8];               \
        oa0 = __builtin_amdgcn_mfma_f32_16x16x32_bf16(pa, vv[2*cc],   oa0, 0, 0, 0); \
        oa1 = __builtin_amdgcn_mfma_f32_16x16x32_bf16(pa, vv[2*cc+1], oa1, 0, 0, 0); \
    }                                                                              \
}

    for (int jt0 = 0; jt0 < NN; jt0 += 256) {        // 9 outer iters x 2 tiles
        ATTN_PHASE(ba, bb, jt0,       jt0 + 128, true)
        ATTN_PHASE(bb, ba, jt0 + 128, jt0 + 256, (jt0 + 256 < NN))
    }
#undef ATTN_PHASE

    // row-sum reduction across the 16 l15 lanes (stays within quad group)
    #pragma unroll
    for (int r = 0; r < 4; ++r) {
        #pragma unroll
        for (int off = 1; off < 16; off <<= 1)
            l_r[r] += __shfl_xor(l_r[r], off, 64);
    }

    // epilogue: normalize, write bf16 to ao[b][i][h*32+d]
    unsigned short* aop = ao + ((size_t)b * NN + i0) * HID + h * DH;
    #pragma unroll
    for (int r = 0; r < 4; ++r) {
        const int row = quad * 4 + r;
        const float inv = 1.0f / l_r[r];
        aop[(size_t)row * HID + l15]      = f2bf(oa0[r] * inv);
        aop[(size_t)row * HID + 16 + l15] = f2bf(oa1[r] * inv);
    }
}

// ---------------------------------------------------------------------------
// K3: out projection, bf16 MFMA.
// out[b][o][n] = sum_c w_out[o][c] * ao[b][n][c] + b_out[o]
// ---------------------------------------------------------------------------
__global__ __launch_bounds__(256) void out_proj(const unsigned short* __restrict__ wob,
                                                const unsigned short* __restrict__ aob,
                                                const float* __restrict__ bout,
                                                float* __restrict__ out) {
    const int n0 = blockIdx.x * 64;
    const int o0 = blockIdx.y * 64;
    const int b  = blockIdx.z;
    const int t = threadIdx.x;
    const int w = t >> 6, lane = t & 63, l15 = lane & 15, quad = lane >> 4;
    const int orow = o0 + w * 16;

    float4v acc[4] = {{0.f,0.f,0.f,0.f},{0.f,0.f,0.f,0.f},
                      {0.f,0.f,0.f,0.f},{0.f,0.f,0.f,0.f}};
    const unsigned short* ap = aob + ((size_t)b * NN + n0) * HID;
    #pragma unroll
    for (int c0 = 0; c0 < HID; c0 += 32) {
        short8 af = *(const short8*)(wob + (size_t)(orow + l15) * HID + c0 + quad * 8);
        #pragma unroll
        for (int jj = 0; jj < 4; ++jj) {
            short8 bf = *(const short8*)(ap + (size_t)(jj * 16 + l15) * HID + c0 + quad * 8);
            acc[jj] = __builtin_amdgcn_mfma_f32_16x16x32_bf16(af, bf, acc[jj], 0, 0, 0);
        }
    }
    float* op = out + (size_t)b * HID * NN;
    #pragma unroll
    for (int r = 0; r < 4; ++r) {
        const int o = orow + quad * 4 + r;
        const float bv = bout[o];
        #pragma unroll
        for (int jj = 0; jj < 4; ++jj)
            op[(size_t)o * NN + n0 + jj * 16 + l15] = acc[jj][r] + bv;
    }
}

// ---------------------------------------------------------------------------
extern "C" void kernel_launch(void* const* d_in, const int* in_sizes, int n_in,
                              void* d_out, int out_size, void* d_ws, size_t ws_size,
                              hipStream_t stream) {
    const float* x        = (const float*)d_in[0];  // [4][256][2304]
    const float* pos_bias = (const float*)d_in[1];  // [8][2304][2304]
    const float* w_qkv    = (const float*)d_in[2];  // [768][256]
    const float* w_out    = (const float*)d_in[3];  // [256][256]
    const float* b_out    = (const float*)d_in[4];  // [256]
    float* out = (float*)d_out;                     // [4][256][2304]

    // workspace carve-up (256B-aligned); total ~24.5 MB (proven-safe size)
    char* ws = (char*)d_ws;
    unsigned short* q   = (unsigned short*)(ws);                      //  4,718,592
    unsigned short* k   = (unsigned short*)(ws + 4718592);            //  4,718,592
    unsigned short* v   = (unsigned short*)(ws + 9437184);            //  4,718,592
    unsigned short* ao  = (unsigned short*)(ws + 14155776);           //  4,718,592
    unsigned short* wob = (unsigned short*)(ws + 18874368);           //    131,072
    unsigned short* whi = (unsigned short*)(ws + 19005440);           //    393,216
    unsigned short* wlo = (unsigned short*)(ws + 19398656);           //    393,216
    unsigned short* xT  = (unsigned short*)(ws + 19791872);           //  4,718,592

    prep_kernel<<<3072, 256, 0, stream>>>(x, w_qkv, w_out, xT, whi, wlo, wob);
    qkv_gemm_bf16<<<dim3(12, NN / 64, BB), 256, 0, stream>>>(xT, whi, wlo, q, k, v);
    attn_kernel<<<dim3(NN / 16, NH), 256, 0, stream>>>(q, k, v, pos_bias, ao);
    out_proj<<<dim3(NN / 64, HID / 64, BB), 256, 0, stream>>>(wob, ao, b_out, out);
}

// Round 8
// 432.967 us; speedup vs baseline: 1.0049x; 1.0049x over previous
//
#include <hip/hip_runtime.h>
#include <stdint.h>
#include <stddef.h>

// Problem constants
#define BB 4
#define CC 256
#define NH 8
#define DH 32
#define NN 2304      // 48*48
#define O3 768
#define HID 256
#define QK_SCALE 0.17677669529663687f  // 32^-0.5
#define LOG2E 1.44269504f

typedef __attribute__((ext_vector_type(8))) short short8;
typedef __attribute__((ext_vector_type(4))) float float4v;

__device__ __forceinline__ unsigned short f2bf(float f) {
    union { float f; uint32_t u; } v; v.f = f;
    uint32_t u = v.u;
    return (unsigned short)((u + 0x7FFFu + ((u >> 16) & 1u)) >> 16);   // RNE
}
__device__ __forceinline__ float bf2f(unsigned short s) {
    union { uint32_t u; float f; } v; v.u = ((uint32_t)s) << 16;
    return v.f;
}

// ---------------------------------------------------------------------------
// K0: prep = transpose-cast x -> xT bf16  (blocks 0..2303)
//          + cast w_qkv hi/lo, w_out      (blocks 2304..3071)
// ---------------------------------------------------------------------------
__global__ __launch_bounds__(256) void prep_kernel(const float* __restrict__ x,
                                                   const float* __restrict__ wqkv,
                                                   const float* __restrict__ wout,
                                                   unsigned short* __restrict__ xT,
                                                   unsigned short* __restrict__ whi,
                                                   unsigned short* __restrict__ wlo,
                                                   unsigned short* __restrict__ wob) {
    const int bid = blockIdx.x;
    const int t = threadIdx.x;
    if (bid < 2304) {      // transpose 32x32 tile of x
        const int n0 = (bid % 72) * 32, c0 = ((bid / 72) % 8) * 32, b = bid / 576;
        __shared__ float ls[32][33];
        {
            int c = t >> 3, nc = (t & 7) * 4;
            float4 v4 = *(const float4*)(x + ((size_t)b * CC + c0 + c) * NN + n0 + nc);
            ls[c][nc] = v4.x; ls[c][nc + 1] = v4.y; ls[c][nc + 2] = v4.z; ls[c][nc + 3] = v4.w;
        }
        __syncthreads();
        {
            int n = t >> 3, cl = (t & 7) * 4;
            uint32_t p0 = (uint32_t)f2bf(ls[cl + 0][n]) | ((uint32_t)f2bf(ls[cl + 1][n]) << 16);
            uint32_t p1 = (uint32_t)f2bf(ls[cl + 2][n]) | ((uint32_t)f2bf(ls[cl + 3][n]) << 16);
            uint32_t* dst = (uint32_t*)(xT + ((size_t)b * NN + n0 + n) * CC + c0 + cl);
            dst[0] = p0; dst[1] = p1;
        }
    } else {               // weight casts
        int i = (bid - 2304) * 256 + t;
        float wv = wqkv[i];
        unsigned short hi = f2bf(wv);
        whi[i] = hi;
        wlo[i] = f2bf(wv - bf2f(hi));
        if (i < HID * HID) wob[i] = f2bf(wout[i]);
    }
}

// ---------------------------------------------------------------------------
// K1 v2: fused QKV projection, SOFTWARE-PIPELINED (round-8).
// The old kernel's B loads (bh/bl) sat directly in front of their MFMAs in
// an 8-step K-loop -> serialized ~200-900cy load->use chains. Now: the
// read-once operand (A) is hoisted fully into registers up-front, and the
// per-k-step operand is register double-buffered one step ahead via a
// hand-written 2-phase unroll (static indices). No barriers; 8-14 loads in
// flight per wave continuously. Output code & layouts unchanged:
//   q,k bf16 [b][h][n][32] (q scaled by QK_SCALE*LOG2E), v bf16 [b][h][32][n]
// ---------------------------------------------------------------------------
__global__ __launch_bounds__(256) void qkv_gemm_bf16(const unsigned short* __restrict__ xT,
                                                     const unsigned short* __restrict__ whi,
                                                     const unsigned short* __restrict__ wlo,
                                                     unsigned short* __restrict__ q,
                                                     unsigned short* __restrict__ k,
                                                     unsigned short* __restrict__ v) {
    const int og = blockIdx.x;
    const int n0 = blockIdx.y * 64;
    const int b  = blockIdx.z;
    const int t = threadIdx.x;
    const int w = t >> 6, lane = t & 63, l15 = lane & 15, quad = lane >> 4;
    const unsigned short* xb = xT + (size_t)b * NN * CC;

    float4v acc[4] = {{0.f,0.f,0.f,0.f},{0.f,0.f,0.f,0.f},
                      {0.f,0.f,0.f,0.f},{0.f,0.f,0.f,0.f}};

    if (og < 8) {   // ---- qk mode: A = xT rows n (read-once), B = w rows o ----
        const int o0 = og * 64;
        const unsigned short* ap = xb + (size_t)(n0 + w * 16 + l15) * CC + quad * 8;
        const unsigned short* wp = whi + (size_t)(o0 + l15) * CC + quad * 8;
        const unsigned short* lp = wlo + (size_t)(o0 + l15) * CC + quad * 8;

        // A: all 8 k-step fragments up-front (independent, deep in flight)
        short8 A[8];
        #pragma unroll
        for (int c = 0; c < 8; ++c) A[c] = *(const short8*)(ap + c * 32);

        // B: register double-buffer, one k-step ahead
        short8 bhA[4], blA[4], bhB[4], blB[4];
        #pragma unroll
        for (int jj = 0; jj < 4; ++jj) {
            bhA[jj] = *(const short8*)(wp + (size_t)jj * 16 * CC);
            blA[jj] = *(const short8*)(lp + (size_t)jj * 16 * CC);
        }

#define QK_STEP(CH, CL, NH_, NL_, C0, HAVE)                                        \
{                                                                                  \
    if (HAVE) {                                                                    \
        _Pragma("unroll")                                                          \
        for (int jj = 0; jj < 4; ++jj) {                                           \
            NH_[jj] = *(const short8*)(wp + (size_t)jj * 16 * CC + ((C0) + 1) * 32); \
            NL_[jj] = *(const short8*)(lp + (size_t)jj * 16 * CC + ((C0) + 1) * 32); \
        }                                                                          \
    }                                                                              \
    _Pragma("unroll")                                                              \
    for (int jj = 0; jj < 4; ++jj) {                                               \
        acc[jj] = __builtin_amdgcn_mfma_f32_16x16x32_bf16(A[C0], CH[jj], acc[jj], 0, 0, 0); \
        acc[jj] = __builtin_amdgcn_mfma_f32_16x16x32_bf16(A[C0], CL[jj], acc[jj], 0, 0, 0); \
    }                                                                              \
}
        QK_STEP(bhA, blA, bhB, blB, 0, true)
        QK_STEP(bhB, blB, bhA, blA, 1, true)
        QK_STEP(bhA, blA, bhB, blB, 2, true)
        QK_STEP(bhB, blB, bhA, blA, 3, true)
        QK_STEP(bhA, blA, bhB, blB, 4, true)
        QK_STEP(bhB, blB, bhA, blA, 5, true)
        QK_STEP(bhA, blA, bhB, blB, 6, true)
        QK_STEP(bhB, blB, bhA, blA, 7, false)
#undef QK_STEP

        #pragma unroll
        for (int jj = 0; jj < 4; ++jj) {
            const int o = o0 + jj * 16 + l15;
            const int which = o >> 8;            // 0=q 1=k
            const int h = (o >> 5) & 7, d = o & 31;
            unsigned short* dst = which ? k : q;
            const float sc = which ? 1.0f : QK_SCALE * LOG2E;
            #pragma unroll
            for (int r = 0; r < 4; ++r) {
                const int n = n0 + w * 16 + quad * 4 + r;
                dst[(((size_t)b * NH + h) * NN + n) * DH + d] = f2bf(acc[jj][r] * sc);
            }
        }
    } else {        // ---- v mode: A = w rows o, B = xT rows n ----
        const int o0 = 512 + (og - 8) * 64;
        const unsigned short* awp = whi + (size_t)(o0 + w * 16 + l15) * CC + quad * 8;
        const unsigned short* alp = wlo + (size_t)(o0 + w * 16 + l15) * CC + quad * 8;
        const unsigned short* bp_ = xb + (size_t)(n0 + l15) * CC + quad * 8;

        short8 ahA, alA, ahB, alB, bA[4], bB[4];
        ahA = *(const short8*)(awp);
        alA = *(const short8*)(alp);
        #pragma unroll
        for (int jj = 0; jj < 4; ++jj)
            bA[jj] = *(const short8*)(bp_ + (size_t)jj * 16 * CC);

#define V_STEP(CAH, CAL, CB, NAH, NAL, NB, C0, HAVE)                               \
{                                                                                  \
    if (HAVE) {                                                                    \
        NAH = *(const short8*)(awp + ((C0) + 1) * 32);                             \
        NAL = *(const short8*)(alp + ((C0) + 1) * 32);                             \
        _Pragma("unroll")                                                          \
        for (int jj = 0; jj < 4; ++jj)                                             \
            NB[jj] = *(const short8*)(bp_ + (size_t)jj * 16 * CC + ((C0) + 1) * 32); \
    }                                                                              \
    _Pragma("unroll")                                                              \
    for (int jj = 0; jj < 4; ++jj) {                                               \
        acc[jj] = __builtin_amdgcn_mfma_f32_16x16x32_bf16(CAH, CB[jj], acc[jj], 0, 0, 0); \
        acc[jj] = __builtin_amdgcn_mfma_f32_16x16x32_bf16(CAL, CB[jj], acc[jj], 0, 0, 0); \
    }                                                                              \
}
        V_STEP(ahA, alA, bA, ahB, alB, bB, 0, true)
        V_STEP(ahB, alB, bB, ahA, alA, bA, 1, true)
        V_STEP(ahA, alA, bA, ahB, alB, bB, 2, true)
        V_STEP(ahB, alB, bB, ahA, alA, bA, 3, true)
        V_STEP(ahA, alA, bA, ahB, alB, bB, 4, true)
        V_STEP(ahB, alB, bB, ahA, alA, bA, 5, true)
        V_STEP(ahA, alA, bA, ahB, alB, bB, 6, true)
        V_STEP(ahB, alB, bB, ahA, alA, bA, 7, false)
#undef V_STEP

        #pragma unroll
        for (int r = 0; r < 4; ++r) {
            const int o = o0 + w * 16 + quad * 4 + r;
            const int h = (o >> 5) & 7, d = o & 31;
            #pragma unroll
            for (int jj = 0; jj < 4; ++jj) {
                const int n = n0 + jj * 16 + l15;
                v[(((size_t)b * NH + h) * DH + d) * NN + n] = f2bf(acc[jj][r]);
            }
        }
    }
}

// ---------------------------------------------------------------------------
// K2: fused attention v7 — BARRIER-FREE, register-resident bias pipeline.
// (unchanged from round 7: 182us, FETCH 130MB — serves as the A/B control.)
// ---------------------------------------------------------------------------
__global__ __launch_bounds__(256) void attn_kernel(const unsigned short* __restrict__ qg,
                                                   const unsigned short* __restrict__ kg,
                                                   const unsigned short* __restrict__ vg,
                                                   const float* __restrict__ bias,
                                                   unsigned short* __restrict__ ao) {
    const int i0   = blockIdx.x * 16;
    const int h    = blockIdx.y;
    const int t    = threadIdx.x;
    const int b    = t >> 6;            // wave index = batch index (BB==4)
    const int lane = t & 63;
    const int l15  = lane & 15;
    const int quad = lane >> 4;

    __shared__ unsigned short ps[BB][16][136];   // 17.4 KB, wave-private rows

    const size_t bh = (size_t)b * NH + h;
    const unsigned short* qp = qg + bh * NN * DH;
    const unsigned short* kp = kg + bh * NN * DH;
    const unsigned short* vp = vg + bh * DH * NN;

    short8 qf = *(const short8*)(qp + (size_t)(i0 + l15) * DH + quad * 8);

    float4v oa0 = {0.f, 0.f, 0.f, 0.f};
    float4v oa1 = {0.f, 0.f, 0.f, 0.f};
    float l_r[4] = {0.f, 0.f, 0.f, 0.f};

    const float* bp = bias + ((size_t)h * NN + i0 + quad * 4) * NN + l15;

    float ba[32], bb[32];
    #pragma unroll
    for (int r = 0; r < 4; ++r)
        #pragma unroll
        for (int jj = 0; jj < 8; ++jj)
            ba[r * 8 + jj] = bp[(size_t)r * NN + jj * 16];

#define ATTN_PHASE(BC, BN, JT, PJT, HAVEP)                                         \
{                                                                                  \
    short8 kf[8];                                                                  \
    _Pragma("unroll")                                                              \
    for (int jj = 0; jj < 8; ++jj)                                                 \
        kf[jj] = *(const short8*)(kp + (size_t)((JT) + jj * 16 + l15) * DH + quad * 8); \
    short8 vv[8];                                                                  \
    _Pragma("unroll")                                                              \
    for (int cc = 0; cc < 4; ++cc) {                                               \
        vv[2*cc]   = *(const short8*)(vp + (size_t)l15 * NN      + (JT) + cc*32 + quad*8); \
        vv[2*cc+1] = *(const short8*)(vp + (size_t)(l15+16) * NN + (JT) + cc*32 + quad*8); \
    }                                                                              \
    if (HAVEP) {                                                                   \
        _Pragma("unroll")                                                          \
        for (int r = 0; r < 4; ++r)                                                \
            _Pragma("unroll")                                                      \
            for (int jj = 0; jj < 8; ++jj)                                         \
                BN[r * 8 + jj] = bp[(size_t)r * NN + (PJT) + jj * 16];             \
    }                                                                              \
    float4v s[8];                                                                  \
    _Pragma("unroll")                                                              \
    for (int jj = 0; jj < 8; ++jj) {                                               \
        float4v ci = { BC[0*8+jj] * LOG2E, BC[1*8+jj] * LOG2E,                     \
                       BC[2*8+jj] * LOG2E, BC[3*8+jj] * LOG2E };                   \
        s[jj] = __builtin_amdgcn_mfma_f32_16x16x32_bf16(qf, kf[jj], ci, 0, 0, 0);  \
    }                                                                              \
    _Pragma("unroll")                                                              \
    for (int r = 0; r < 4; ++r) {                                                  \
        const int row = quad * 4 + r;                                              \
        float pv_[8];                                                              \
        _Pragma("unroll")                                                          \
        for (int jj = 0; jj < 8; ++jj) { pv_[jj] = exp2f(s[jj][r]); l_r[r] += pv_[jj]; } \
        _Pragma("unroll")                                                          \
        for (int jp = 0; jp < 4; ++jp) {                                           \
            uint32_t pk;                                                           \
            asm("v_cvt_pk_bf16_f32 %0, %1, %2" : "=v"(pk) : "v"(pv_[2*jp]), "v"(pv_[2*jp+1])); \
            ps[b][row][(2*jp)   * 16 + l15] = (unsigned short)pk;                  \
            ps[b][row][(2*jp+1) * 16 + l15] = (unsigned short)(pk >> 16);          \
        }                                                                          \
    }                                                                              \
    _Pragma("unroll")                                                              \
    for (int cc = 0; cc < 4; ++cc) {                                               \
        short8 pa = *(const short8*)&ps[b][l15][cc * 32 + quad * 8];               \
        oa0 = __builtin_amdgcn_mfma_f32_16x16x32_bf16(pa, vv[2*cc],   oa0, 0, 0, 0); \
        oa1 = __builtin_amdgcn_mfma_f32_16x16x32_bf16(pa, vv[2*cc+1], oa1, 0, 0, 0); \
    }                                                                              \
}

    for (int jt0 = 0; jt0 < NN; jt0 += 256) {        // 9 outer iters x 2 tiles
        ATTN_PHASE(ba, bb, jt0,       jt0 + 128, true)
        ATTN_PHASE(bb, ba, jt0 + 128, jt0 + 256, (jt0 + 256 < NN))
    }
#undef ATTN_PHASE

    #pragma unroll
    for (int r = 0; r < 4; ++r) {
        #pragma unroll
        for (int off = 1; off < 16; off <<= 1)
            l_r[r] += __shfl_xor(l_r[r], off, 64);
    }

    unsigned short* aop = ao + ((size_t)b * NN + i0) * HID + h * DH;
    #pragma unroll
    for (int r = 0; r < 4; ++r) {
        const int row = quad * 4 + r;
        const float inv = 1.0f / l_r[r];
        aop[(size_t)row * HID + l15]      = f2bf(oa0[r] * inv);
        aop[(size_t)row * HID + 16 + l15] = f2bf(oa1[r] * inv);
    }
}

// ---------------------------------------------------------------------------
// K3 v2: out projection, SOFTWARE-PIPELINED like K1.
// A (wob rows, read-once per wave) hoisted fully to registers; B (ao rows)
// register double-buffered one k-step ahead. No barriers.
// out[b][o][n] = sum_c w_out[o][c] * ao[b][n][c] + b_out[o]
// ---------------------------------------------------------------------------
__global__ __launch_bounds__(256) void out_proj(const unsigned short* __restrict__ wob,
                                                const unsigned short* __restrict__ aob,
                                                const float* __restrict__ bout,
                                                float* __restrict__ out) {
    const int n0 = blockIdx.x * 64;
    const int o0 = blockIdx.y * 64;
    const int b  = blockIdx.z;
    const int t = threadIdx.x;
    const int w = t >> 6, lane = t & 63, l15 = lane & 15, quad = lane >> 4;
    const int orow = o0 + w * 16;

    float4v acc[4] = {{0.f,0.f,0.f,0.f},{0.f,0.f,0.f,0.f},
                      {0.f,0.f,0.f,0.f},{0.f,0.f,0.f,0.f}};
    const unsigned short* ap = aob + ((size_t)b * NN + n0) * HID;
    const unsigned short* wpp = wob + (size_t)(orow + l15) * HID + quad * 8;
    const unsigned short* bpp = ap + (size_t)l15 * HID + quad * 8;

    short8 A[8];
    #pragma unroll
    for (int c = 0; c < 8; ++c) A[c] = *(const short8*)(wpp + c * 32);

    short8 bA[4], bB[4];
    #pragma unroll
    for (int jj = 0; jj < 4; ++jj)
        bA[jj] = *(const short8*)(bpp + (size_t)jj * 16 * HID);

#define OP_STEP(CB, NB, C0, HAVE)                                                  \
{                                                                                  \
    if (HAVE) {                                                                    \
        _Pragma("unroll")                                                          \
        for (int jj = 0; jj < 4; ++jj)                                             \
            NB[jj] = *(const short8*)(bpp + (size_t)jj * 16 * HID + ((C0) + 1) * 32); \
    }                                                                              \
    _Pragma("unroll")                                                              \
    for (int jj = 0; jj < 4; ++jj)                                                 \
        acc[jj] = __builtin_amdgcn_mfma_f32_16x16x32_bf16(A[C0], CB[jj], acc[jj], 0, 0, 0); \
}
    OP_STEP(bA, bB, 0, true)
    OP_STEP(bB, bA, 1, true)
    OP_STEP(bA, bB, 2, true)
    OP_STEP(bB, bA, 3, true)
    OP_STEP(bA, bB, 4, true)
    OP_STEP(bB, bA, 5, true)
    OP_STEP(bA, bB, 6, true)
    OP_STEP(bB, bA, 7, false)
#undef OP_STEP

    float* op = out + (size_t)b * HID * NN;
    #pragma unroll
    for (int r = 0; r < 4; ++r) {
        const int o = orow + quad * 4 + r;
        const float bv = bout[o];
        #pragma unroll
        for (int jj = 0; jj < 4; ++jj)
            op[(size_t)o * NN + n0 + jj * 16 + l15] = acc[jj][r] + bv;
    }
}

// ---------------------------------------------------------------------------
extern "C" void kernel_launch(void* const* d_in, const int* in_sizes, int n_in,
                              void* d_out, int out_size, void* d_ws, size_t ws_size,
                              hipStream_t stream) {
    const float* x        = (const float*)d_in[0];  // [4][256][2304]
    const float* pos_bias = (const float*)d_in[1];  // [8][2304][2304]
    const float* w_qkv    = (const float*)d_in[2];  // [768][256]
    const float* w_out    = (const float*)d_in[3];  // [256][256]
    const float* b_out    = (const float*)d_in[4];  // [256]
    float* out = (float*)d_out;                     // [4][256][2304]

    // workspace carve-up (256B-aligned); total ~24.5 MB (proven-safe size)
    char* ws = (char*)d_ws;
    unsigned short* q   = (unsigned short*)(ws);                      //  4,718,592
    unsigned short* k   = (unsigned short*)(ws + 4718592);            //  4,718,592
    unsigned short* v   = (unsigned short*)(ws + 9437184);            //  4,718,592
    unsigned short* ao  = (unsigned short*)(ws + 14155776);           //  4,718,592
    unsigned short* wob = (unsigned short*)(ws + 18874368);           //    131,072
    unsigned short* whi = (unsigned short*)(ws + 19005440);           //    393,216
    unsigned short* wlo = (unsigned short*)(ws + 19398656);           //    393,216
    unsigned short* xT  = (unsigned short*)(ws + 19791872);           //  4,718,592

    prep_kernel<<<3072, 256, 0, stream>>>(x, w_qkv, w_out, xT, whi, wlo, wob);
    qkv_gemm_bf16<<<dim3(12, NN / 64, BB), 256, 0, stream>>>(xT, whi, wlo, q, k, v);
    attn_kernel<<<dim3(NN / 16, NH), 256, 0, stream>>>(q, k, v, pos_bias, ao);
    out_proj<<<dim3(NN / 64, HID / 64, BB), 256, 0, stream>>>(wob, ao, b_out, out);
}